// Round 3
// baseline (542.172 us; speedup 1.0000x reference)
//
#include <hip/hip_runtime.h>
#include <stdint.h>

#define K_DIM 512
#define N_OUT 512
#define BM 64
#define BK 64

typedef __bf16 bf16x8 __attribute__((ext_vector_type(8)));
typedef float f32x4 __attribute__((ext_vector_type(4)));
typedef unsigned short ushort8 __attribute__((ext_vector_type(8)));

__device__ inline unsigned short f2bf(float f) {
  unsigned u = __float_as_uint(f);
  u += 0x7fffu + ((u >> 16) & 1u);
  return (unsigned short)(u >> 16);
}

// ---------------- prep: W fp32->bf16 + zero the scatter accumulator -------------
__global__ __launch_bounds__(256) void prep_kernel(const float* __restrict__ W,
                                                   unsigned short* __restrict__ wb,
                                                   float* __restrict__ s,
                                                   int n8w, int M) {
  int i = blockIdx.x * 256 + threadIdx.x;
  if (i < n8w) {
    const float4* sp = (const float4*)W + (size_t)i * 2;
    float4 a = sp[0], c = sp[1];
    ushort8 o;
    o[0] = f2bf(a.x); o[1] = f2bf(a.y); o[2] = f2bf(a.z); o[3] = f2bf(a.w);
    o[4] = f2bf(c.x); o[5] = f2bf(c.y); o[6] = f2bf(c.z); o[7] = f2bf(c.w);
    *(ushort8*)(wb + (size_t)i * 8) = o;
  } else {
    int j = i - n8w;
    if (j < M) s[j] = 0.f;
  }
}

// ---------------- scatter pre-pass: s[col[e]] += x[e,0] -------------------------
__global__ __launch_bounds__(256) void scatter_s_kernel(const float* __restrict__ x,
                                                        const int* __restrict__ ei,
                                                        float* __restrict__ s, int E) {
  int e = blockIdx.x * 256 + threadIdx.x;
  if (e < E) {
    int c = ei[E + e];
    atomicAdd(s + c, x[(size_t)e * K_DIM]);
  }
}

// ---------------- GEMM v3: BM=64 x BN=512 (full width) --------------------------
// x streamed ONCE (no column-strip re-read). A: f32->regs->cvt->LDS (16KB dbuf).
// B (W bf16, 512KB, L2-resident): loaded global->registers per fragment — no LDS,
// no barrier dependency. The only loads drained by __syncthreads are A(t+1),
// which the cvt already waited on -> barrier drain costs nothing extra.
// Per-wave in-flight bytes ~8KB (vs ~320B before) -> fixes latency starvation.
__global__ __launch_bounds__(256) void gemm_fused3_kernel(
    const float* __restrict__ x, const unsigned short* __restrict__ wb,
    const float* __restrict__ b, const float* __restrict__ s,
    float* __restrict__ out, int M) {
  __shared__ __align__(16) unsigned short Als[2][BM * BK];  // 2 x 8 KB

  const int tid = threadIdx.x;
  const int lane = tid & 63;
  const int quad = lane >> 4;
  const int l16 = lane & 15;
  const int waveId = tid >> 6;   // 0..3
  const int wn = waveId * 128;   // wave's 128-col strip of the 512-wide output
  const int blockM = blockIdx.x * BM;

  // A staging: 512 chunks (64 rows x 8 chunks of 8 elems); thread owns 2 chunks.
  // Global source chunk XOR-swizzled so fragment ds_read_b128 is conflict-free.
  size_t goffA[2];
  int ldsoff[2];
#pragma unroll
  for (int i = 0; i < 2; ++i) {
    int ch = i * 256 + tid;
    int row = ch >> 3;        // 0..63
    int c8 = ch & 7;
    int sc = c8 ^ (row & 7);
    int ga_row = blockM + row;
    if (ga_row > M - 1) ga_row = M - 1;  // clamp tail (masked in epilogue)
    goffA[i] = (size_t)ga_row * K_DIM + sc * 8;  // f32 elements
    ldsoff[i] = ch * 8;                          // bf16 elements
  }

  // B row-base pointers: one per ni (16-row group). Inner-loop offset k0+ss*32
  // elements (<=960B) folds into the load's immediate.
  const unsigned short* pB[8];
#pragma unroll
  for (int ni = 0; ni < 8; ++ni)
    pB[ni] = wb + (size_t)(wn + ni * 16 + l16) * K_DIM + quad * 8;

  f32x4 acc[4][8] = {};
  float4 a0[2], a1[2];

  // ---- prologue: stage A K-tile 0 into buffer 0 ----
#pragma unroll
  for (int i = 0; i < 2; ++i) {
    a0[i] = *(const float4*)(x + goffA[i]);
    a1[i] = *(const float4*)(x + goffA[i] + 4);
  }
#pragma unroll
  for (int i = 0; i < 2; ++i) {
    ushort8 o;
    o[0] = f2bf(a0[i].x); o[1] = f2bf(a0[i].y); o[2] = f2bf(a0[i].z); o[3] = f2bf(a0[i].w);
    o[4] = f2bf(a1[i].x); o[5] = f2bf(a1[i].y); o[6] = f2bf(a1[i].z); o[7] = f2bf(a1[i].w);
    *(ushort8*)(&Als[0][ldsoff[i]]) = o;
  }
  __syncthreads();

  int cur = 0;
  for (int k0 = 0; k0 < K_DIM; k0 += BK) {
    const int nxt = cur ^ 1;
    const bool has_next = (k0 + BK) < K_DIM;

    // issue A(t+1) f32 loads — land during compute; cvt waits on them after
    if (has_next) {
#pragma unroll
      for (int i = 0; i < 2; ++i) {
        a0[i] = *(const float4*)(x + goffA[i] + k0 + BK);
        a1[i] = *(const float4*)(x + goffA[i] + k0 + BK + 4);
      }
    }

    // compute on A buffer[cur]; B fragments straight from global (L1/L2-hot W)
#pragma unroll
    for (int ss = 0; ss < 2; ++ss) {
      bf16x8 af[4];
#pragma unroll
      for (int mi = 0; mi < 4; ++mi) {
        int rr = mi * 16 + l16;
        int c = (ss * 4 + quad) ^ (rr & 7);
        af[mi] = *(const bf16x8*)(&Als[cur][rr * BK + c * 8]);
      }
      bf16x8 bfr[8];
#pragma unroll
      for (int ni = 0; ni < 8; ++ni)
        bfr[ni] = *(const bf16x8*)(pB[ni] + k0 + ss * 32);
#pragma unroll
      for (int mi = 0; mi < 4; ++mi)
#pragma unroll
        for (int ni = 0; ni < 8; ++ni)
          acc[mi][ni] = __builtin_amdgcn_mfma_f32_16x16x32_bf16(af[mi], bfr[ni], acc[mi][ni], 0, 0, 0);
    }

    // cvt + write A(t+1) into buffer[nxt] (disjoint from readers of cur)
    if (has_next) {
#pragma unroll
      for (int i = 0; i < 2; ++i) {
        ushort8 o;
        o[0] = f2bf(a0[i].x); o[1] = f2bf(a0[i].y); o[2] = f2bf(a0[i].z); o[3] = f2bf(a0[i].w);
        o[4] = f2bf(a1[i].x); o[5] = f2bf(a1[i].y); o[6] = f2bf(a1[i].z); o[7] = f2bf(a1[i].w);
        *(ushort8*)(&Als[nxt][ldsoff[i]]) = o;
      }
    }

    __syncthreads();
    cur = nxt;
  }

  // epilogue: bias + relu + scatter-add (col 0); C/D layout col=lane&15,
  // row=quad*4+reg (m89/m91). Nontemporal: out never re-read; keep x/W in caches.
#pragma unroll
  for (int ni = 0; ni < 8; ++ni) {
    int gcol = wn + ni * 16 + l16;
    float bias = b[gcol];
#pragma unroll
    for (int mi = 0; mi < 4; ++mi) {
#pragma unroll
      for (int rr = 0; rr < 4; ++rr) {
        int grow = blockM + mi * 16 + quad * 4 + rr;
        if (grow < M) {
          float v = acc[mi][ni][rr] + bias;
          v = v > 0.f ? v : 0.f;
          if (gcol == 0) v += s[grow];  // relu first, then scatter-add (matches ref)
          __builtin_nontemporal_store(v, out + (size_t)grow * N_OUT + gcol);
        }
      }
    }
  }
}

// ---------------- fallback: fused-conversion GEMM (if ws too small) -------------
#define FBM 128
#define FBN 128
#define LDS_STRIDE 40
__global__ __launch_bounds__(256) void gemm_fused_kernel(
    const float* __restrict__ x, const float* __restrict__ W,
    const float* __restrict__ b, float* __restrict__ out, int M) {
  __shared__ __align__(16) unsigned short Als[FBM * LDS_STRIDE];
  __shared__ __align__(16) unsigned short Bls[FBN * LDS_STRIDE];
  const int tid = threadIdx.x;
  const int lane = tid & 63;
  const int quad = lane >> 4;
  const int l16 = lane & 15;
  const int waveId = tid >> 6;
  const int wm = (waveId >> 1) * 64;
  const int wn = (waveId & 1) * 64;
  const int blockM = blockIdx.y * FBM;
  const int blockN = blockIdx.x * FBN;
  f32x4 acc[4][4] = {};
  for (int k0 = 0; k0 < K_DIM; k0 += 32) {
#pragma unroll
    for (int i = 0; i < 4; ++i) {
      int idx = i * 256 + tid;
      int row = idx >> 3;
      int c4 = idx & 7;
      float4 va = make_float4(0.f, 0.f, 0.f, 0.f);
      int grow = blockM + row;
      if (grow < M) va = *(const float4*)(x + (size_t)grow * K_DIM + k0 + c4 * 4);
      ushort4 ha;
      ha.x = f2bf(va.x); ha.y = f2bf(va.y); ha.z = f2bf(va.z); ha.w = f2bf(va.w);
      *(ushort4*)(&Als[row * LDS_STRIDE + c4 * 4]) = ha;
      float4 vb = *(const float4*)(W + (size_t)(blockN + row) * K_DIM + k0 + c4 * 4);
      ushort4 hb;
      hb.x = f2bf(vb.x); hb.y = f2bf(vb.y); hb.z = f2bf(vb.z); hb.w = f2bf(vb.w);
      *(ushort4*)(&Bls[row * LDS_STRIDE + c4 * 4]) = hb;
    }
    __syncthreads();
    bf16x8 af[4], bfr[4];
#pragma unroll
    for (int mi = 0; mi < 4; ++mi)
      af[mi] = *(const bf16x8*)(&Als[(wm + mi * 16 + l16) * LDS_STRIDE + quad * 8]);
#pragma unroll
    for (int ni = 0; ni < 4; ++ni)
      bfr[ni] = *(const bf16x8*)(&Bls[(wn + ni * 16 + l16) * LDS_STRIDE + quad * 8]);
#pragma unroll
    for (int mi = 0; mi < 4; ++mi)
#pragma unroll
      for (int ni = 0; ni < 4; ++ni)
        acc[mi][ni] = __builtin_amdgcn_mfma_f32_16x16x32_bf16(af[mi], bfr[ni], acc[mi][ni], 0, 0, 0);
    __syncthreads();
  }
#pragma unroll
  for (int ni = 0; ni < 4; ++ni) {
    int gcol = blockN + wn + ni * 16 + l16;
    float bias = b[gcol];
#pragma unroll
    for (int mi = 0; mi < 4; ++mi) {
#pragma unroll
      for (int rr = 0; rr < 4; ++rr) {
        int grow = blockM + wm + mi * 16 + quad * 4 + rr;
        if (grow < M) {
          float v = acc[mi][ni][rr] + bias;
          out[(size_t)grow * N_OUT + gcol] = v > 0.f ? v : 0.f;
        }
      }
    }
  }
}

// fallback scatter: out[col[e], 0] += x[e, 0]
__global__ void scatter_kernel(const float* __restrict__ x,
                               const int* __restrict__ ei,
                               float* __restrict__ out, int E) {
  int e = blockIdx.x * 256 + threadIdx.x;
  if (e < E) {
    int c = ei[E + e];
    atomicAdd(out + (size_t)c * N_OUT, x[(size_t)e * K_DIM]);
  }
}

extern "C" void kernel_launch(void* const* d_in, const int* in_sizes, int n_in,
                              void* d_out, int out_size, void* d_ws, size_t ws_size,
                              hipStream_t stream) {
  const float* x = (const float*)d_in[0];
  const int* ei = (const int*)d_in[1];
  const float* W = (const float*)d_in[2];
  const float* b = (const float*)d_in[3];
  float* out = (float*)d_out;

  int M = in_sizes[0] / K_DIM;  // 100000
  int E = in_sizes[1] / 2;      // 100000

  size_t w_elems = (size_t)N_OUT * K_DIM;            // 262,144
  size_t need = w_elems * 2 + (size_t)M * 4 + 64;    // wb (bf16) + s (f32)

  if (ws_size >= need) {
    unsigned short* wb = (unsigned short*)d_ws;
    float* s = (float*)((char*)d_ws + w_elems * 2);  // 512 KB offset, 16B aligned
    int n8w = (int)(w_elems / 8);  // 32,768
    int prep_total = n8w + M;
    prep_kernel<<<(prep_total + 255) / 256, 256, 0, stream>>>(W, wb, s, n8w, M);
    scatter_s_kernel<<<(E + 255) / 256, 256, 0, stream>>>(x, ei, s, E);
    int nblk = (M + BM - 1) / BM;  // 1563
    gemm_fused3_kernel<<<nblk, 256, 0, stream>>>(x, wb, b, s, out, M);
  } else {
    dim3 fgrid(N_OUT / FBN, (M + FBM - 1) / FBM);
    gemm_fused_kernel<<<fgrid, 256, 0, stream>>>(x, W, b, out, M);
    scatter_kernel<<<(E + 255) / 256, 256, 0, stream>>>(x, ei, out, E);
  }
}

// Round 5
// 452.924 us; speedup vs baseline: 1.1971x; 1.1971x over previous
//
#include <hip/hip_runtime.h>
#include <stdint.h>

#define K_DIM 512
#define N_OUT 512
#define BM 128
#define BN 128
#define BK 64

typedef __bf16 bf16x8 __attribute__((ext_vector_type(8)));
typedef float f32x4 __attribute__((ext_vector_type(4)));
typedef unsigned short ushort8 __attribute__((ext_vector_type(8)));

__device__ inline unsigned short f2bf(float f) {
  unsigned u = __float_as_uint(f);
  u += 0x7fffu + ((u >> 16) & 1u);
  return (unsigned short)(u >> 16);
}

// ---------------- prep (grid-stride): cvt x->xb, cvt W->wb, zero s, densify x0 --
// x f32 is dead after this pass -> nontemporal loads (don't evict xb from L3).
// Column 0 of x is densified into x0[] so the scatter pass reads coalesced.
__global__ __launch_bounds__(256) void prep_all_kernel(
    const float* __restrict__ x, unsigned short* __restrict__ xb,
    const float* __restrict__ W, unsigned short* __restrict__ wb,
    float* __restrict__ x0, float* __restrict__ s,
    int n8x, int n8w, int n8s) {
  const int stride = gridDim.x * 256;
  const int total = n8x + n8w + n8s;
  for (int i = blockIdx.x * 256 + threadIdx.x; i < total; i += stride) {
    if (i < n8x) {
      const f32x4* sp = (const f32x4*)x + (size_t)i * 2;
      f32x4 a = __builtin_nontemporal_load(sp);
      f32x4 c = __builtin_nontemporal_load(sp + 1);
      ushort8 o;
      o[0] = f2bf(a[0]); o[1] = f2bf(a[1]); o[2] = f2bf(a[2]); o[3] = f2bf(a[3]);
      o[4] = f2bf(c[0]); o[5] = f2bf(c[1]); o[6] = f2bf(c[2]); o[7] = f2bf(c[3]);
      *(ushort8*)(xb + (size_t)i * 8) = o;
      // chunk i covers flat elements [8i, 8i+8); row r's col-0 is flat r*512 = 8*(64r)
      if ((i & 63) == 0) x0[i >> 6] = a[0];
    } else if (i < n8x + n8w) {
      int j = i - n8x;
      const f32x4* sp = (const f32x4*)W + (size_t)j * 2;
      f32x4 a = sp[0], c = sp[1];
      ushort8 o;
      o[0] = f2bf(a[0]); o[1] = f2bf(a[1]); o[2] = f2bf(a[2]); o[3] = f2bf(a[3]);
      o[4] = f2bf(c[0]); o[5] = f2bf(c[1]); o[6] = f2bf(c[2]); o[7] = f2bf(c[3]);
      *(ushort8*)(wb + (size_t)j * 8) = o;
    } else {
      int j = i - n8x - n8w;
      f32x4 z = {0.f, 0.f, 0.f, 0.f};
      *(f32x4*)(s + (size_t)j * 8) = z;
      *(f32x4*)(s + (size_t)j * 8 + 4) = z;
    }
  }
}

// ---------------- scatter pre-pass: s[col[e]] += x0[e] (coalesced read) ---------
__global__ __launch_bounds__(256) void scatter_s_kernel(const float* __restrict__ x0,
                                                        const int* __restrict__ ei,
                                                        float* __restrict__ s, int E) {
  int e = blockIdx.x * 256 + threadIdx.x;
  if (e < E) {
    atomicAdd(s + ei[E + e], x0[e]);
  }
}

// ---------------- GEMM: R0 m97 structure (proven 164us) + XCD swizzle + fused
//                  epilogue (bias+relu+s-add, nontemporal C stores) --------------
__global__ __launch_bounds__(256) void gemm_bf16_kernel(
    const unsigned short* __restrict__ xb, const unsigned short* __restrict__ wb,
    const float* __restrict__ b, const float* __restrict__ s,
    float* __restrict__ out, int M) {
  __shared__ __align__(16) unsigned short Als[BM * BK];  // 16 KB, unpadded (global_load_lds)
  __shared__ __align__(16) unsigned short Bls[BN * BK];  // 16 KB

  const int tid = threadIdx.x;
  const int lane = tid & 63;
  const int quad = lane >> 4;
  const int l16 = lane & 15;
  const int waveId = tid >> 6;
  const int wm = (waveId >> 1) * 64;
  const int wn = (waveId & 1) * 64;

  // m204 bijective XCD remap: 4 column-tiles of one x row-band run consecutively
  // on one XCD -> A-panel served from that XCD's L2 (proved FETCH 203->104 MB).
  const int nwg = gridDim.x * gridDim.y;  // 3128, %8 == 0
  int raw = blockIdx.y * gridDim.x + blockIdx.x;
  int q = nwg >> 3, r = nwg & 7;
  int xcd = raw & 7;
  int wg = (xcd < r ? xcd * (q + 1) : r * (q + 1) + (xcd - r) * q) + (raw >> 3);
  const int blockM = (wg >> 2) * BM;  // gridDim.x == N_OUT/BN == 4
  const int blockN = (wg & 3) * BN;

  // staging: thread owns LDS 16B-chunk ch = i*256+tid (lane-contiguous per wave,
  // required by global_load_lds); global source chunk XOR-swizzled so fragment
  // ds_read_b128 spreads across all 32 banks.
  size_t goffA[4], goffB[4];
  int ldsoff[4];
#pragma unroll
  for (int i = 0; i < 4; ++i) {
    int ch = i * 256 + tid;
    int row = ch >> 3;       // 0..127
    int c8 = ch & 7;         // 16B chunk within 128B row
    int sc = c8 ^ (row & 7); // swizzled global chunk
    int ga_row = blockM + row;
    if (ga_row > M - 1) ga_row = M - 1;  // clamp tail (masked in epilogue)
    goffA[i] = (size_t)ga_row * K_DIM + sc * 8;
    goffB[i] = (size_t)(blockN + row) * K_DIM + sc * 8;
    ldsoff[i] = ch * 8;  // elements; *2B = ch*16 bytes
  }

  f32x4 acc[4][4] = {};

  for (int k0 = 0; k0 < K_DIM; k0 += BK) {
#pragma unroll
    for (int i = 0; i < 4; ++i) {
      __builtin_amdgcn_global_load_lds(
          (const __attribute__((address_space(1))) void*)(xb + goffA[i] + k0),
          (__attribute__((address_space(3))) void*)(&Als[ldsoff[i]]), 16, 0, 0);
      __builtin_amdgcn_global_load_lds(
          (const __attribute__((address_space(1))) void*)(wb + goffB[i] + k0),
          (__attribute__((address_space(3))) void*)(&Bls[ldsoff[i]]), 16, 0, 0);
    }
    __syncthreads();

#pragma unroll
    for (int ss = 0; ss < 2; ++ss) {  // two K=32 steps within BK=64
      bf16x8 af[4], bfr[4];
#pragma unroll
      for (int mi = 0; mi < 4; ++mi) {
        int rr = wm + mi * 16 + l16;
        int c = (ss * 4 + quad) ^ (rr & 7);
        af[mi] = *(const bf16x8*)(&Als[rr * BK + c * 8]);
      }
#pragma unroll
      for (int ni = 0; ni < 4; ++ni) {
        int rr = wn + ni * 16 + l16;
        int c = (ss * 4 + quad) ^ (rr & 7);
        bfr[ni] = *(const bf16x8*)(&Bls[rr * BK + c * 8]);
      }
#pragma unroll
      for (int mi = 0; mi < 4; ++mi)
#pragma unroll
        for (int ni = 0; ni < 4; ++ni)
          acc[mi][ni] = __builtin_amdgcn_mfma_f32_16x16x32_bf16(af[mi], bfr[ni], acc[mi][ni], 0, 0, 0);
    }
    __syncthreads();
  }

  // epilogue: bias + relu + scatter-add (col 0); C/D layout col=lane&15,
  // row=quad*4+reg (m89/m91). Nontemporal: out never re-read; keep xb in L3.
#pragma unroll
  for (int ni = 0; ni < 4; ++ni) {
    int gcol = blockN + wn + ni * 16 + l16;
    float bias = b[gcol];
#pragma unroll
    for (int mi = 0; mi < 4; ++mi) {
#pragma unroll
      for (int rr = 0; rr < 4; ++rr) {
        int grow = blockM + wm + mi * 16 + quad * 4 + rr;
        if (grow < M) {
          float v = acc[mi][ni][rr] + bias;
          v = v > 0.f ? v : 0.f;
          if (gcol == 0) v += s[grow];  // relu first, then scatter-add (matches ref)
          __builtin_nontemporal_store(v, out + (size_t)grow * N_OUT + gcol);
        }
      }
    }
  }
}

// ---------------- fallback: fused-conversion GEMM (if ws too small) -------------
#define LDS_STRIDE 40
__global__ __launch_bounds__(256) void gemm_fused_kernel(
    const float* __restrict__ x, const float* __restrict__ W,
    const float* __restrict__ b, float* __restrict__ out, int M) {
  __shared__ __align__(16) unsigned short Als[BM * LDS_STRIDE];
  __shared__ __align__(16) unsigned short Bls[BN * LDS_STRIDE];
  const int tid = threadIdx.x;
  const int lane = tid & 63;
  const int quad = lane >> 4;
  const int l16 = lane & 15;
  const int waveId = tid >> 6;
  const int wm = (waveId >> 1) * 64;
  const int wn = (waveId & 1) * 64;
  const int blockM = blockIdx.y * BM;
  const int blockN = blockIdx.x * BN;
  f32x4 acc[4][4] = {};
  for (int k0 = 0; k0 < K_DIM; k0 += 32) {
#pragma unroll
    for (int i = 0; i < 4; ++i) {
      int idx = i * 256 + tid;
      int row = idx >> 3;
      int c4 = idx & 7;
      float4 va = make_float4(0.f, 0.f, 0.f, 0.f);
      int grow = blockM + row;
      if (grow < M) va = *(const float4*)(x + (size_t)grow * K_DIM + k0 + c4 * 4);
      ushort4 ha;
      ha.x = f2bf(va.x); ha.y = f2bf(va.y); ha.z = f2bf(va.z); ha.w = f2bf(va.w);
      *(ushort4*)(&Als[row * LDS_STRIDE + c4 * 4]) = ha;
      float4 vb = *(const float4*)(W + (size_t)(blockN + row) * K_DIM + k0 + c4 * 4);
      ushort4 hb;
      hb.x = f2bf(vb.x); hb.y = f2bf(vb.y); hb.z = f2bf(vb.z); hb.w = f2bf(vb.w);
      *(ushort4*)(&Bls[row * LDS_STRIDE + c4 * 4]) = hb;
    }
    __syncthreads();
    bf16x8 af[4], bfr[4];
#pragma unroll
    for (int mi = 0; mi < 4; ++mi)
      af[mi] = *(const bf16x8*)(&Als[(wm + mi * 16 + l16) * LDS_STRIDE + quad * 8]);
#pragma unroll
    for (int ni = 0; ni < 4; ++ni)
      bfr[ni] = *(const bf16x8*)(&Bls[(wn + ni * 16 + l16) * LDS_STRIDE + quad * 8]);
#pragma unroll
    for (int mi = 0; mi < 4; ++mi)
#pragma unroll
      for (int ni = 0; ni < 4; ++ni)
        acc[mi][ni] = __builtin_amdgcn_mfma_f32_16x16x32_bf16(af[mi], bfr[ni], acc[mi][ni], 0, 0, 0);
    __syncthreads();
  }
#pragma unroll
  for (int ni = 0; ni < 4; ++ni) {
    int gcol = blockN + wn + ni * 16 + l16;
    float bias = b[gcol];
#pragma unroll
    for (int mi = 0; mi < 4; ++mi) {
#pragma unroll
      for (int rr = 0; rr < 4; ++rr) {
        int grow = blockM + wm + mi * 16 + quad * 4 + rr;
        if (grow < M) {
          float v = acc[mi][ni][rr] + bias;
          out[(size_t)grow * N_OUT + gcol] = v > 0.f ? v : 0.f;
        }
      }
    }
  }
}

// fallback scatter: out[col[e], 0] += x[e, 0]
__global__ void scatter_kernel(const float* __restrict__ x,
                               const int* __restrict__ ei,
                               float* __restrict__ out, int E) {
  int e = blockIdx.x * 256 + threadIdx.x;
  if (e < E) {
    int c = ei[E + e];
    atomicAdd(out + (size_t)c * N_OUT, x[(size_t)e * K_DIM]);
  }
}

extern "C" void kernel_launch(void* const* d_in, const int* in_sizes, int n_in,
                              void* d_out, int out_size, void* d_ws, size_t ws_size,
                              hipStream_t stream) {
  const float* x = (const float*)d_in[0];
  const int* ei = (const int*)d_in[1];
  const float* W = (const float*)d_in[2];
  const float* b = (const float*)d_in[3];
  float* out = (float*)d_out;

  int M = in_sizes[0] / K_DIM;  // 100000
  int E = in_sizes[1] / 2;      // 100000

  size_t x_elems = (size_t)M * K_DIM;      // 51,200,000
  size_t w_elems = (size_t)N_OUT * K_DIM;  // 262,144
  int n8x = (int)(x_elems / 8);            // 6,400,000 (K_DIM%8==0)
  int n8w = (int)(w_elems / 8);            // 32,768
  int n8s = (M + 7) / 8;                   // 12,500
  size_t s_elems = (size_t)n8s * 8;        // s rounded to 8 so zeroing can't spill

  // ws layout: xb (bf16) | wb (bf16) | s (f32) | x0 (f32)
  size_t need = x_elems * 2 + w_elems * 2 + s_elems * 4 + (size_t)M * 4;

  dim3 grid(N_OUT / BN, (M + BM - 1) / BM);  // (4, 782) -> nwg=3128, %8==0

  if (ws_size >= need) {
    unsigned short* xb = (unsigned short*)d_ws;
    unsigned short* wb = xb + x_elems;
    float* s = (float*)(wb + w_elems);
    float* x0 = s + s_elems;

    int total = n8x + n8w + n8s;
    int pblk = (total + 255) / 256;
    if (pblk > 2048) pblk = 2048;  // grid-stride
    prep_all_kernel<<<pblk, 256, 0, stream>>>(x, xb, W, wb, x0, s, n8x, n8w, n8s);
    scatter_s_kernel<<<(E + 255) / 256, 256, 0, stream>>>(x0, ei, s, E);
    gemm_bf16_kernel<<<grid, 256, 0, stream>>>(xb, wb, b, s, out, M);
  } else {
    gemm_fused_kernel<<<grid, 256, 0, stream>>>(x, W, b, out, M);
    scatter_kernel<<<(E + 255) / 256, 256, 0, stream>>>(x, ei, out, E);
  }
}

// Round 6
// 440.158 us; speedup vs baseline: 1.2318x; 1.0290x over previous
//
#include <hip/hip_runtime.h>
#include <stdint.h>

#define K_DIM 512
#define N_OUT 512
#define BM 128
#define BN 128
#define BK 64
#define NT 8  // K_DIM / BK tiles

typedef __bf16 bf16x8 __attribute__((ext_vector_type(8)));
typedef float f32x4 __attribute__((ext_vector_type(4)));
typedef unsigned short ushort8 __attribute__((ext_vector_type(8)));

__device__ inline unsigned short f2bf(float f) {
  unsigned u = __float_as_uint(f);
  u += 0x7fffu + ((u >> 16) & 1u);
  return (unsigned short)(u >> 16);
}

// ---------------- prep (grid-stride): cvt x->xb, cvt W->wb, zero s, densify x0 --
__global__ __launch_bounds__(256) void prep_all_kernel(
    const float* __restrict__ x, unsigned short* __restrict__ xb,
    const float* __restrict__ W, unsigned short* __restrict__ wb,
    float* __restrict__ x0, float* __restrict__ s,
    int n8x, int n8w, int n8s) {
  const int stride = gridDim.x * 256;
  const int total = n8x + n8w + n8s;
  for (int i = blockIdx.x * 256 + threadIdx.x; i < total; i += stride) {
    if (i < n8x) {
      const f32x4* sp = (const f32x4*)x + (size_t)i * 2;
      f32x4 a = __builtin_nontemporal_load(sp);
      f32x4 c = __builtin_nontemporal_load(sp + 1);
      ushort8 o;
      o[0] = f2bf(a[0]); o[1] = f2bf(a[1]); o[2] = f2bf(a[2]); o[3] = f2bf(a[3]);
      o[4] = f2bf(c[0]); o[5] = f2bf(c[1]); o[6] = f2bf(c[2]); o[7] = f2bf(c[3]);
      *(ushort8*)(xb + (size_t)i * 8) = o;
      if ((i & 63) == 0) x0[i >> 6] = a[0];  // densify col 0 (row r at chunk 64r)
    } else if (i < n8x + n8w) {
      int j = i - n8x;
      const f32x4* sp = (const f32x4*)W + (size_t)j * 2;
      f32x4 a = sp[0], c = sp[1];
      ushort8 o;
      o[0] = f2bf(a[0]); o[1] = f2bf(a[1]); o[2] = f2bf(a[2]); o[3] = f2bf(a[3]);
      o[4] = f2bf(c[0]); o[5] = f2bf(c[1]); o[6] = f2bf(c[2]); o[7] = f2bf(c[3]);
      *(ushort8*)(wb + (size_t)j * 8) = o;
    } else {
      int j = i - n8x - n8w;
      f32x4 z = {0.f, 0.f, 0.f, 0.f};
      *(f32x4*)(s + (size_t)j * 8) = z;
      *(f32x4*)(s + (size_t)j * 8 + 4) = z;
    }
  }
}

// ---------------- scatter pre-pass: s[col[e]] += x0[e] (coalesced read) ---------
__global__ __launch_bounds__(256) void scatter_s_kernel(const float* __restrict__ x0,
                                                        const int* __restrict__ ei,
                                                        float* __restrict__ s, int E) {
  int e = blockIdx.x * 256 + threadIdx.x;
  if (e < E) {
    atomicAdd(s + ei[E + e], x0[e]);
  }
}

// ---------------- GEMM: m97 core + T3/T4 counted-vmcnt double-buffer + T5 -------
// Per tile t: vmcnt(8) [tile t's 8 loads done, tile t+1's 8 stay IN FLIGHT across
// the barrier] -> s_barrier -> ds_read+MFMA (setprio 1) -> s_barrier -> stage
// tile t+2 into the freed buffer. No __syncthreads in the loop => no compiler
// vmcnt(0) drain. Raw-barrier correctness: each thread's own waits cover its own
// loads; barrier makes that collective. ds_reads are plain loads so the compiler
// tracks lgkm deps into the MFMAs (no manual lgkm needed).
__global__ __launch_bounds__(256) void gemm_bf16_kernel(
    const unsigned short* __restrict__ xb, const unsigned short* __restrict__ wb,
    const float* __restrict__ b, const float* __restrict__ s,
    float* __restrict__ out, int M) {
  __shared__ __align__(16) unsigned short Als[2][BM * BK];  // 2 x 16 KB
  __shared__ __align__(16) unsigned short Bls[2][BN * BK];  // 2 x 16 KB

  const int tid = threadIdx.x;
  const int lane = tid & 63;
  const int quad = lane >> 4;
  const int l16 = lane & 15;
  const int waveId = tid >> 6;
  const int wm = (waveId >> 1) * 64;
  const int wn = (waveId & 1) * 64;

  // m204 bijective XCD remap (proved FETCH 203->52 MB with L3).
  const int nwg = gridDim.x * gridDim.y;  // 3128, %8 == 0
  int raw = blockIdx.y * gridDim.x + blockIdx.x;
  int q = nwg >> 3, r = nwg & 7;
  int xcd = raw & 7;
  int wg = (xcd < r ? xcd * (q + 1) : r * (q + 1) + (xcd - r) * q) + (raw >> 3);
  const int blockM = (wg >> 2) * BM;  // gridDim.x == N_OUT/BN == 4
  const int blockN = (wg & 3) * BN;

  // staging: thread owns LDS 16B-chunk ch (lane-contiguous per wave, required by
  // global_load_lds); global source chunk XOR-swizzled -> conflict-free ds_read_b128.
  size_t goffA[4], goffB[4];
  int ldsoff[4];
#pragma unroll
  for (int i = 0; i < 4; ++i) {
    int ch = i * 256 + tid;
    int row = ch >> 3;
    int c8 = ch & 7;
    int sc = c8 ^ (row & 7);
    int ga_row = blockM + row;
    if (ga_row > M - 1) ga_row = M - 1;  // clamp tail (masked in epilogue)
    goffA[i] = (size_t)ga_row * K_DIM + sc * 8;
    goffB[i] = (size_t)(blockN + row) * K_DIM + sc * 8;
    ldsoff[i] = ch * 8;
  }

#define STAGE(buf, k0)                                                              \
  {                                                                                 \
    _Pragma("unroll") for (int i = 0; i < 4; ++i) {                                 \
      __builtin_amdgcn_global_load_lds(                                             \
          (const __attribute__((address_space(1))) void*)(xb + goffA[i] + (k0)),    \
          (__attribute__((address_space(3))) void*)(&Als[buf][ldsoff[i]]), 16, 0, 0);\
      __builtin_amdgcn_global_load_lds(                                             \
          (const __attribute__((address_space(1))) void*)(wb + goffB[i] + (k0)),    \
          (__attribute__((address_space(3))) void*)(&Bls[buf][ldsoff[i]]), 16, 0, 0);\
    }                                                                               \
  }

  f32x4 acc[4][4] = {};

  // prologue: tiles 0 and 1 in flight (16 loads)
  STAGE(0, 0);
  STAGE(1, BK);

#pragma unroll
  for (int t = 0; t < NT; ++t) {
    // counted wait: tile t's 8 loads done; tile t+1's 8 remain in flight
    if (t < NT - 1) {
      asm volatile("s_waitcnt vmcnt(8)" ::: "memory");
    } else {
      asm volatile("s_waitcnt vmcnt(0)" ::: "memory");
    }
    __builtin_amdgcn_s_barrier();

    const int cur = t & 1;
#pragma unroll
    for (int ss = 0; ss < 2; ++ss) {  // two K=32 steps within BK=64
      bf16x8 af[4], bfr[4];
#pragma unroll
      for (int mi = 0; mi < 4; ++mi) {
        int rr = wm + mi * 16 + l16;
        int c = (ss * 4 + quad) ^ (rr & 7);
        af[mi] = *(const bf16x8*)(&Als[cur][rr * BK + c * 8]);
      }
#pragma unroll
      for (int ni = 0; ni < 4; ++ni) {
        int rr = wn + ni * 16 + l16;
        int c = (ss * 4 + quad) ^ (rr & 7);
        bfr[ni] = *(const bf16x8*)(&Bls[cur][rr * BK + c * 8]);
      }
      __builtin_amdgcn_s_setprio(1);
#pragma unroll
      for (int mi = 0; mi < 4; ++mi)
#pragma unroll
        for (int ni = 0; ni < 4; ++ni)
          acc[mi][ni] = __builtin_amdgcn_mfma_f32_16x16x32_bf16(af[mi], bfr[ni], acc[mi][ni], 0, 0, 0);
      __builtin_amdgcn_s_setprio(0);
    }

    // all waves done reading buf[cur] (their lgkm waits precede their last MFMA)
    __builtin_amdgcn_s_barrier();
    if (t + 2 < NT) {
      STAGE(cur, (t + 2) * BK);  // refill the freed buffer; +8 in flight
    }
  }
#undef STAGE

  // epilogue: bias + relu + scatter-add (col 0); C/D layout col=lane&15,
  // row=quad*4+reg (m89/m91). Nontemporal: out never re-read; keep xb in L3.
#pragma unroll
  for (int ni = 0; ni < 4; ++ni) {
    int gcol = blockN + wn + ni * 16 + l16;
    float bias = b[gcol];
#pragma unroll
    for (int mi = 0; mi < 4; ++mi) {
#pragma unroll
      for (int rr = 0; rr < 4; ++rr) {
        int grow = blockM + wm + mi * 16 + quad * 4 + rr;
        if (grow < M) {
          float v = acc[mi][ni][rr] + bias;
          v = v > 0.f ? v : 0.f;
          if (gcol == 0) v += s[grow];  // relu first, then scatter-add (matches ref)
          __builtin_nontemporal_store(v, out + (size_t)grow * N_OUT + gcol);
        }
      }
    }
  }
}

// ---------------- fallback: fused-conversion GEMM (if ws too small) -------------
#define LDS_STRIDE 40
__global__ __launch_bounds__(256) void gemm_fused_kernel(
    const float* __restrict__ x, const float* __restrict__ W,
    const float* __restrict__ b, float* __restrict__ out, int M) {
  __shared__ __align__(16) unsigned short Als[BM * LDS_STRIDE];
  __shared__ __align__(16) unsigned short Bls[BN * LDS_STRIDE];
  const int tid = threadIdx.x;
  const int lane = tid & 63;
  const int quad = lane >> 4;
  const int l16 = lane & 15;
  const int waveId = tid >> 6;
  const int wm = (waveId >> 1) * 64;
  const int wn = (waveId & 1) * 64;
  const int blockM = blockIdx.y * BM;
  const int blockN = blockIdx.x * BN;
  f32x4 acc[4][4] = {};
  for (int k0 = 0; k0 < K_DIM; k0 += 32) {
#pragma unroll
    for (int i = 0; i < 4; ++i) {
      int idx = i * 256 + tid;
      int row = idx >> 3;
      int c4 = idx & 7;
      float4 va = make_float4(0.f, 0.f, 0.f, 0.f);
      int grow = blockM + row;
      if (grow < M) va = *(const float4*)(x + (size_t)grow * K_DIM + k0 + c4 * 4);
      ushort4 ha;
      ha.x = f2bf(va.x); ha.y = f2bf(va.y); ha.z = f2bf(va.z); ha.w = f2bf(va.w);
      *(ushort4*)(&Als[row * LDS_STRIDE + c4 * 4]) = ha;
      float4 vb = *(const float4*)(W + (size_t)(blockN + row) * K_DIM + k0 + c4 * 4);
      ushort4 hb;
      hb.x = f2bf(vb.x); hb.y = f2bf(vb.y); hb.z = f2bf(vb.z); hb.w = f2bf(vb.w);
      *(ushort4*)(&Bls[row * LDS_STRIDE + c4 * 4]) = hb;
    }
    __syncthreads();
    bf16x8 af[4], bfr[4];
#pragma unroll
    for (int mi = 0; mi < 4; ++mi)
      af[mi] = *(const bf16x8*)(&Als[(wm + mi * 16 + l16) * LDS_STRIDE + quad * 8]);
#pragma unroll
    for (int ni = 0; ni < 4; ++ni)
      bfr[ni] = *(const bf16x8*)(&Bls[(wn + ni * 16 + l16) * LDS_STRIDE + quad * 8]);
#pragma unroll
    for (int mi = 0; mi < 4; ++mi)
#pragma unroll
      for (int ni = 0; ni < 4; ++ni)
        acc[mi][ni] = __builtin_amdgcn_mfma_f32_16x16x32_bf16(af[mi], bfr[ni], acc[mi][ni], 0, 0, 0);
    __syncthreads();
  }
#pragma unroll
  for (int ni = 0; ni < 4; ++ni) {
    int gcol = blockN + wn + ni * 16 + l16;
    float bias = b[gcol];
#pragma unroll
    for (int mi = 0; mi < 4; ++mi) {
#pragma unroll
      for (int rr = 0; rr < 4; ++rr) {
        int grow = blockM + wm + mi * 16 + quad * 4 + rr;
        if (grow < M) {
          float v = acc[mi][ni][rr] + bias;
          out[(size_t)grow * N_OUT + gcol] = v > 0.f ? v : 0.f;
        }
      }
    }
  }
}

// fallback scatter: out[col[e], 0] += x[e, 0]
__global__ void scatter_kernel(const float* __restrict__ x,
                               const int* __restrict__ ei,
                               float* __restrict__ out, int E) {
  int e = blockIdx.x * 256 + threadIdx.x;
  if (e < E) {
    int c = ei[E + e];
    atomicAdd(out + (size_t)c * N_OUT, x[(size_t)e * K_DIM]);
  }
}

extern "C" void kernel_launch(void* const* d_in, const int* in_sizes, int n_in,
                              void* d_out, int out_size, void* d_ws, size_t ws_size,
                              hipStream_t stream) {
  const float* x = (const float*)d_in[0];
  const int* ei = (const int*)d_in[1];
  const float* W = (const float*)d_in[2];
  const float* b = (const float*)d_in[3];
  float* out = (float*)d_out;

  int M = in_sizes[0] / K_DIM;  // 100000
  int E = in_sizes[1] / 2;      // 100000

  size_t x_elems = (size_t)M * K_DIM;      // 51,200,000
  size_t w_elems = (size_t)N_OUT * K_DIM;  // 262,144
  int n8x = (int)(x_elems / 8);            // 6,400,000
  int n8w = (int)(w_elems / 8);            // 32,768
  int n8s = (M + 7) / 8;                   // 12,500
  size_t s_elems = (size_t)n8s * 8;

  // ws layout: xb (bf16) | wb (bf16) | s (f32) | x0 (f32)
  size_t need = x_elems * 2 + w_elems * 2 + s_elems * 4 + (size_t)M * 4;

  dim3 grid(N_OUT / BN, (M + BM - 1) / BM);  // (4, 782) -> nwg=3128, %8==0

  if (ws_size >= need) {
    unsigned short* xb = (unsigned short*)d_ws;
    unsigned short* wb = xb + x_elems;
    float* s = (float*)(wb + w_elems);
    float* x0 = s + s_elems;

    int total = n8x + n8w + n8s;
    int pblk = (total + 255) / 256;
    if (pblk > 2048) pblk = 2048;  // grid-stride
    prep_all_kernel<<<pblk, 256, 0, stream>>>(x, xb, W, wb, x0, s, n8x, n8w, n8s);
    scatter_s_kernel<<<(E + 255) / 256, 256, 0, stream>>>(x0, ei, s, E);
    gemm_bf16_kernel<<<grid, 256, 0, stream>>>(xb, wb, b, s, out, M);
  } else {
    gemm_fused_kernel<<<grid, 256, 0, stream>>>(x, W, b, out, M);
    scatter_kernel<<<(E + 255) / 256, 256, 0, stream>>>(x, ei, out, E);
  }
}